// Round 4
// baseline (114.002 us; speedup 1.0000x reference)
//
#include <hip/hip_runtime.h>
#include <math.h>

#define HIDDEN 1024
#define VOCAB 50257
#define K2_BLOCKS 2048
#define K2_WAVES (K2_BLOCKS * 4)

__device__ __forceinline__ float wave_reduce_sum(float v) {
#pragma unroll
    for (int m = 1; m < 64; m <<= 1) v += __shfl_xor(v, m, 64);
    return v;
}

// K1: GRU gates + h_new. One block per hidden unit j, one wave per gate g.
// Also zeroes the K2 completion counter (stream-ordered before K2).
__global__ __launch_bounds__(192) void gru_kernel(
    const int* token_p, const float* __restrict__ hidden, const float* __restrict__ emb,
    const float* __restrict__ w_ih, const float* __restrict__ w_hh,
    const float* __restrict__ b_ih, const float* __restrict__ b_hh,
    float* __restrict__ h_new_out, unsigned int* __restrict__ counter) {
    const int g = threadIdx.x >> 6;       // gate 0..2 (r, z, n)
    const int lane = threadIdx.x & 63;
    const int j = blockIdx.x;             // 0..1023

    if (blockIdx.x == 0 && threadIdx.x == 0) *counter = 0u;

    const int token = token_p[0];         // low word of the int64 token
    const float4* x4 = (const float4*)(emb + (size_t)token * HIDDEN);
    const float4* h4 = (const float4*)hidden;
    const float4* wi = (const float4*)(w_ih + (size_t)(g * HIDDEN + j) * HIDDEN);
    const float4* wh = (const float4*)(w_hh + (size_t)(g * HIDDEN + j) * HIDDEN);

    float acc_i = 0.f, acc_h = 0.f;
#pragma unroll
    for (int k = 0; k < 4; ++k) {
        const int idx = k * 64 + lane;
        float4 e = x4[idx];
        float4 h = h4[idx];
        float4 a = wi[idx];
        float4 b = wh[idx];
        e.x = fmaxf(e.x, 0.f); e.y = fmaxf(e.y, 0.f);
        e.z = fmaxf(e.z, 0.f); e.w = fmaxf(e.w, 0.f);
        acc_i += a.x * e.x + a.y * e.y + a.z * e.z + a.w * e.w;
        acc_h += b.x * h.x + b.y * h.y + b.z * h.z + b.w * h.w;
    }
    acc_i = wave_reduce_sum(acc_i);
    acc_h = wave_reduce_sum(acc_h);

    __shared__ float red_i[3], red_h[3];
    if (lane == 0) { red_i[g] = acc_i; red_h[g] = acc_h; }
    __syncthreads();

    if (threadIdx.x == 0) {
        const float i_r = red_i[0] + b_ih[j];
        const float i_z = red_i[1] + b_ih[HIDDEN + j];
        const float i_n = red_i[2] + b_ih[2 * HIDDEN + j];
        const float h_r = red_h[0] + b_hh[j];
        const float h_z = red_h[1] + b_hh[HIDDEN + j];
        const float h_n = red_h[2] + b_hh[2 * HIDDEN + j];
        const float r = 1.f / (1.f + expf(-(i_r + h_r)));
        const float z = 1.f / (1.f + expf(-(i_z + h_z)));
        const float n = tanhf(i_n + r * h_n);
        h_new_out[j] = (1.f - z) * n + z * hidden[j];
    }
}

// K2: logits[v] = h_new . w_out[v] + b_out[v], one wave per row grid-strided.
// Fused per-block online (max, sumexp) partials; the LAST block to finish
// (device-scope atomic counter) combines all partials into scalar[0].
__global__ __launch_bounds__(256) void logits_kernel(
    const float* __restrict__ h_new, const float* __restrict__ w_out,
    const float* __restrict__ b_out, float* __restrict__ logits,
    float* __restrict__ partials, float* __restrict__ scalar,
    unsigned int* __restrict__ counter) {
    const int wave = threadIdx.x >> 6;
    const int lane = threadIdx.x & 63;
    const int gw = blockIdx.x * 4 + wave;   // 0..K2_WAVES-1

    const float4* h4 = (const float4*)h_new;
    float4 hs[4];
#pragma unroll
    for (int k = 0; k < 4; ++k) hs[k] = h4[k * 64 + lane];

    float m = -INFINITY, s = 0.f;
    for (int v = gw; v < VOCAB; v += K2_WAVES) {
        const float4* w4 = (const float4*)(w_out + (size_t)v * HIDDEN);
        float acc = 0.f;
#pragma unroll
        for (int k = 0; k < 4; ++k) {
            float4 w = w4[k * 64 + lane];
            acc += w.x * hs[k].x + w.y * hs[k].y + w.z * hs[k].z + w.w * hs[k].w;
        }
        acc = wave_reduce_sum(acc);
        const float l = acc + b_out[v];
        if (lane == 0) logits[v] = l;
        // online max/sum-exp, wave-uniform (replicated on all lanes)
        if (l > m) { s *= expf(m - l); m = l; }
        s += expf(l - m);
    }

    __shared__ float sm[4], ss[4];
    __shared__ unsigned int is_last;
    if (lane == 0) { sm[wave] = m; ss[wave] = s; }
    __syncthreads();
    if (threadIdx.x == 0) {
        float M = fmaxf(fmaxf(sm[0], sm[1]), fmaxf(sm[2], sm[3]));
        float S = ss[0] * expf(sm[0] - M) + ss[1] * expf(sm[1] - M) +
                  ss[2] * expf(sm[2] - M) + ss[3] * expf(sm[3] - M);
        partials[2 * blockIdx.x] = M;
        partials[2 * blockIdx.x + 1] = S;
        __threadfence();  // device-scope release of the partials write
        const unsigned int old = atomicAdd(counter, 1u);
        is_last = (old == (unsigned int)(gridDim.x - 1)) ? 1u : 0u;
    }
    __syncthreads();

    if (is_last) {
        __threadfence();  // acquire side: see all blocks' partials
        float lm = -INFINITY, ls = 0.f;
        for (int t = threadIdx.x; t < K2_BLOCKS; t += 256) {
            const float pm = partials[2 * t];
            const float ps = partials[2 * t + 1];
            const float M = fmaxf(lm, pm);
            ls = ls * expf(lm - M) + ps * expf(pm - M);
            lm = M;
        }
#pragma unroll
        for (int o = 1; o < 64; o <<= 1) {
            const float pm = __shfl_xor(lm, o, 64);
            const float ps = __shfl_xor(ls, o, 64);
            const float M = fmaxf(lm, pm);
            ls = ls * expf(lm - M) + ps * expf(pm - M);
            lm = M;
        }
        if (lane == 0) { sm[wave] = lm; ss[wave] = ls; }
        __syncthreads();
        if (threadIdx.x == 0) {
            float M = fmaxf(fmaxf(sm[0], sm[1]), fmaxf(sm[2], sm[3]));
            float S = ss[0] * expf(sm[0] - M) + ss[1] * expf(sm[1] - M) +
                      ss[2] * expf(sm[2] - M) + ss[3] * expf(sm[3] - M);
            scalar[0] = M + logf(S);
        }
    }
}

// K3: logp[i] = logits[i] - (m + lse), in place in d_out.
__global__ __launch_bounds__(256) void logp_kernel(
    float* __restrict__ logits, const float* __restrict__ scalar) {
    const int i = blockIdx.x * blockDim.x + threadIdx.x;
    if (i < VOCAB) logits[i] -= scalar[0];
}

extern "C" void kernel_launch(void* const* d_in, const int* in_sizes, int n_in,
                              void* d_out, int out_size, void* d_ws, size_t ws_size,
                              hipStream_t stream) {
    const int*   token  = (const int*)d_in[0];
    const float* hidden = (const float*)d_in[1];
    const float* emb    = (const float*)d_in[2];
    const float* w_ih   = (const float*)d_in[3];
    const float* w_hh   = (const float*)d_in[4];
    const float* b_ih   = (const float*)d_in[5];
    const float* b_hh   = (const float*)d_in[6];
    const float* w_out  = (const float*)d_in[7];
    const float* b_out  = (const float*)d_in[8];

    float* out      = (float*)d_out;         // [0..V)=logp, [V..V+H)=h_new
    float* h_new    = out + VOCAB;
    float* logits   = out;
    float* ws       = (float*)d_ws;
    float* partials = ws;                    // 2 * K2_BLOCKS floats
    float* scalar   = ws + 2 * K2_BLOCKS;    // 1 float: m + lse
    unsigned int* counter = (unsigned int*)(ws + 2 * K2_BLOCKS + 1);

    gru_kernel<<<HIDDEN, 192, 0, stream>>>(token, hidden, emb, w_ih, w_hh,
                                           b_ih, b_hh, h_new, counter);
    logits_kernel<<<K2_BLOCKS, 256, 0, stream>>>(h_new, w_out, b_out, logits,
                                                 partials, scalar, counter);
    logp_kernel<<<(VOCAB + 255) / 256, 256, 0, stream>>>(logits, scalar);
}

// Round 5
// 45.966 us; speedup vs baseline: 2.4801x; 2.4801x over previous
//
#include <hip/hip_runtime.h>
#include <math.h>

#define HIDDEN 1024
#define VOCAB 50257
#define K2_BLOCKS 1024
#define NW (K2_BLOCKS * 4)   // waves in K2

__device__ __forceinline__ float wave_reduce_sum(float v) {
#pragma unroll
    for (int m = 1; m < 64; m <<= 1) v += __shfl_xor(v, m, 64);
    return v;
}

// K1: GRU gates + h_new. One block per hidden unit j, one wave per gate g.
// Writes h_new to d_out (output) AND to an aligned staging copy in ws.
__global__ __launch_bounds__(192) void gru_kernel(
    const int* token_p, const float* __restrict__ hidden, const float* __restrict__ emb,
    const float* __restrict__ w_ih, const float* __restrict__ w_hh,
    const float* __restrict__ b_ih, const float* __restrict__ b_hh,
    float* __restrict__ h_new_out, float* __restrict__ h_new_ws) {
    const int g = threadIdx.x >> 6;       // gate 0..2 (r, z, n)
    const int lane = threadIdx.x & 63;
    const int j = blockIdx.x;             // 0..1023

    const int token = token_p[0];         // low word of the int64 token
    const float4* x4 = (const float4*)(emb + (size_t)token * HIDDEN);
    const float4* h4 = (const float4*)hidden;
    const float4* wi = (const float4*)(w_ih + (size_t)(g * HIDDEN + j) * HIDDEN);
    const float4* wh = (const float4*)(w_hh + (size_t)(g * HIDDEN + j) * HIDDEN);

    float acc_i = 0.f, acc_h = 0.f;
#pragma unroll
    for (int k = 0; k < 4; ++k) {
        const int idx = k * 64 + lane;
        float4 e = x4[idx];
        float4 h = h4[idx];
        float4 a = wi[idx];
        float4 b = wh[idx];
        e.x = fmaxf(e.x, 0.f); e.y = fmaxf(e.y, 0.f);
        e.z = fmaxf(e.z, 0.f); e.w = fmaxf(e.w, 0.f);
        acc_i += a.x * e.x + a.y * e.y + a.z * e.z + a.w * e.w;
        acc_h += b.x * h.x + b.y * h.y + b.z * h.z + b.w * h.w;
    }
    acc_i = wave_reduce_sum(acc_i);
    acc_h = wave_reduce_sum(acc_h);

    __shared__ float red_i[3], red_h[3];
    if (lane == 0) { red_i[g] = acc_i; red_h[g] = acc_h; }
    __syncthreads();

    if (threadIdx.x == 0) {
        const float i_r = red_i[0] + b_ih[j];
        const float i_z = red_i[1] + b_ih[HIDDEN + j];
        const float i_n = red_i[2] + b_ih[2 * HIDDEN + j];
        const float h_r = red_h[0] + b_hh[j];
        const float h_z = red_h[1] + b_hh[HIDDEN + j];
        const float h_n = red_h[2] + b_hh[2 * HIDDEN + j];
        const float r = 1.f / (1.f + expf(-(i_r + h_r)));
        const float z = 1.f / (1.f + expf(-(i_z + h_z)));
        const float n = tanhf(i_n + r * h_n);
        const float hv = (1.f - z) * n + z * hidden[j];
        h_new_out[j] = hv;
        h_new_ws[j] = hv;
    }
}

// K2: logits[v] = h_new . w_out[v] + b_out[v]. One wave per row, two rows per
// iteration (8 dwordx4 in flight), fused per-block online (max,sumexp) partials.
__global__ __launch_bounds__(256) void logits_kernel(
    const float* __restrict__ h_new, const float* __restrict__ w_out,
    const float* __restrict__ b_out, float* __restrict__ logits,
    float* __restrict__ partials) {
    const int wave = threadIdx.x >> 6;
    const int lane = threadIdx.x & 63;
    const int gw = blockIdx.x * 4 + wave;   // 0..NW-1

    const float4* h4 = (const float4*)h_new;  // 16B-aligned ws staging copy
    float4 hs[4];
#pragma unroll
    for (int k = 0; k < 4; ++k) hs[k] = h4[k * 64 + lane];

    float m = -INFINITY, s = 0.f;
    for (int v = gw; v < VOCAB; v += 2 * NW) {
        const int v2 = v + NW;
        const bool has2 = (v2 < VOCAB);
        const float4* w1 = (const float4*)(w_out + (size_t)v * HIDDEN);
        const float4* w2 = (const float4*)(w_out + (size_t)(has2 ? v2 : v) * HIDDEN);
        float a1 = 0.f, a2 = 0.f;
#pragma unroll
        for (int k = 0; k < 4; ++k) {
            const int idx = k * 64 + lane;
            float4 x = w1[idx];
            float4 y = w2[idx];
            a1 += x.x * hs[k].x + x.y * hs[k].y + x.z * hs[k].z + x.w * hs[k].w;
            a2 += y.x * hs[k].x + y.y * hs[k].y + y.z * hs[k].z + y.w * hs[k].w;
        }
        a1 = wave_reduce_sum(a1);
        a2 = wave_reduce_sum(a2);

        const float l1 = a1 + b_out[v];
        if (lane == 0) logits[v] = l1;
        if (l1 > m) { s *= expf(m - l1); m = l1; }
        s += expf(l1 - m);

        if (has2) {
            const float l2 = a2 + b_out[v2];
            if (lane == 0) logits[v2] = l2;
            if (l2 > m) { s *= expf(m - l2); m = l2; }
            s += expf(l2 - m);
        }
    }

    __shared__ float sm[4], ss[4];
    if (lane == 0) { sm[wave] = m; ss[wave] = s; }
    __syncthreads();
    if (threadIdx.x == 0) {
        float M = fmaxf(fmaxf(sm[0], sm[1]), fmaxf(sm[2], sm[3]));
        float S = ss[0] * expf(sm[0] - M) + ss[1] * expf(sm[1] - M) +
                  ss[2] * expf(sm[2] - M) + ss[3] * expf(sm[3] - M);
        partials[2 * blockIdx.x] = M;
        partials[2 * blockIdx.x + 1] = S;
    }
}

// K3: every block redundantly combines the K2_BLOCKS (m,s) pairs (8KB, L2-hot),
// then subtracts the LSE from its slice of logits. No third launch needed.
__global__ __launch_bounds__(256) void finalize_kernel(
    const float* __restrict__ partials, float* __restrict__ logits) {
    const int t = threadIdx.x;
    const int wave = t >> 6;
    const int lane = t & 63;

    float m = -INFINITY, s = 0.f;
#pragma unroll
    for (int i = 0; i < K2_BLOCKS / 256; ++i) {
        const int idx = i * 256 + t;
        const float pm = partials[2 * idx];
        const float ps = partials[2 * idx + 1];
        const float M = fmaxf(m, pm);
        s = s * expf(m - M) + ps * expf(pm - M);
        m = M;
    }
#pragma unroll
    for (int o = 1; o < 64; o <<= 1) {
        const float pm = __shfl_xor(m, o, 64);
        const float ps = __shfl_xor(s, o, 64);
        const float M = fmaxf(m, pm);
        s = s * expf(m - M) + ps * expf(pm - M);
        m = M;
    }
    __shared__ float sm[4], ss[4];
    if (lane == 0) { sm[wave] = m; ss[wave] = s; }
    __syncthreads();
    const float M = fmaxf(fmaxf(sm[0], sm[1]), fmaxf(sm[2], sm[3]));
    const float S = ss[0] * expf(sm[0] - M) + ss[1] * expf(sm[1] - M) +
                    ss[2] * expf(sm[2] - M) + ss[3] * expf(sm[3] - M);
    const float c = M + logf(S);

    // subtract: float4 over [0, 50256), scalar tail for element 50256
    float4* l4 = (float4*)logits;
    const int n4 = VOCAB / 4;  // 12564
    for (int i = blockIdx.x * 256 + t; i < n4; i += gridDim.x * 256) {
        float4 x = l4[i];
        x.x -= c; x.y -= c; x.z -= c; x.w -= c;
        l4[i] = x;
    }
    if (blockIdx.x == 0 && t == 0) logits[VOCAB - 1] -= c;
}

extern "C" void kernel_launch(void* const* d_in, const int* in_sizes, int n_in,
                              void* d_out, int out_size, void* d_ws, size_t ws_size,
                              hipStream_t stream) {
    const int*   token  = (const int*)d_in[0];
    const float* hidden = (const float*)d_in[1];
    const float* emb    = (const float*)d_in[2];
    const float* w_ih   = (const float*)d_in[3];
    const float* w_hh   = (const float*)d_in[4];
    const float* b_ih   = (const float*)d_in[5];
    const float* b_hh   = (const float*)d_in[6];
    const float* w_out  = (const float*)d_in[7];
    const float* b_out  = (const float*)d_in[8];

    float* out      = (float*)d_out;        // [0..V)=logp, [V..V+H)=h_new
    float* h_new    = out + VOCAB;
    float* logits   = out;
    float* ws       = (float*)d_ws;
    float* partials = ws;                   // 2*K2_BLOCKS floats
    float* h_new_ws = ws + 2 * K2_BLOCKS;   // HIDDEN floats, 16B-aligned

    gru_kernel<<<HIDDEN, 192, 0, stream>>>(token, hidden, emb, w_ih, w_hh,
                                           b_ih, b_hh, h_new, h_new_ws);
    logits_kernel<<<K2_BLOCKS, 256, 0, stream>>>(h_new_ws, w_out, b_out, logits,
                                                 partials);
    finalize_kernel<<<64, 256, 0, stream>>>(partials, logits);
}

// Round 6
// 44.764 us; speedup vs baseline: 2.5467x; 1.0269x over previous
//
#include <hip/hip_runtime.h>
#include <math.h>

#define HIDDEN 1024
#define VOCAB 50257
#define K2_BLOCKS 2048
#define NW (K2_BLOCKS * 4)   // 8192 waves in K2

__device__ __forceinline__ float wave_reduce_sum(float v) {
#pragma unroll
    for (int m = 1; m < 64; m <<= 1) v += __shfl_xor(v, m, 64);
    return v;
}

// K1: GRU gates + h_new. One block per hidden unit j, one wave per gate g.
// Writes h_new to d_out (output) AND to an aligned staging copy in ws.
__global__ __launch_bounds__(192) void gru_kernel(
    const int* token_p, const float* __restrict__ hidden, const float* __restrict__ emb,
    const float* __restrict__ w_ih, const float* __restrict__ w_hh,
    const float* __restrict__ b_ih, const float* __restrict__ b_hh,
    float* __restrict__ h_new_out, float* __restrict__ h_new_ws) {
    const int g = threadIdx.x >> 6;       // gate 0..2 (r, z, n)
    const int lane = threadIdx.x & 63;
    const int j = blockIdx.x;             // 0..1023

    const int token = token_p[0];         // low word of the int64 token
    const float4* x4 = (const float4*)(emb + (size_t)token * HIDDEN);
    const float4* h4 = (const float4*)hidden;
    const float4* wi = (const float4*)(w_ih + (size_t)(g * HIDDEN + j) * HIDDEN);
    const float4* wh = (const float4*)(w_hh + (size_t)(g * HIDDEN + j) * HIDDEN);

    float acc_i = 0.f, acc_h = 0.f;
#pragma unroll
    for (int k = 0; k < 4; ++k) {
        const int idx = k * 64 + lane;
        float4 e = x4[idx];
        float4 h = h4[idx];
        float4 a = wi[idx];
        float4 b = wh[idx];
        e.x = fmaxf(e.x, 0.f); e.y = fmaxf(e.y, 0.f);
        e.z = fmaxf(e.z, 0.f); e.w = fmaxf(e.w, 0.f);
        acc_i += a.x * e.x + a.y * e.y + a.z * e.z + a.w * e.w;
        acc_h += b.x * h.x + b.y * h.y + b.z * h.z + b.w * h.w;
    }
    acc_i = wave_reduce_sum(acc_i);
    acc_h = wave_reduce_sum(acc_h);

    __shared__ float red_i[3], red_h[3];
    if (lane == 0) { red_i[g] = acc_i; red_h[g] = acc_h; }
    __syncthreads();

    if (threadIdx.x == 0) {
        const float i_r = red_i[0] + b_ih[j];
        const float i_z = red_i[1] + b_ih[HIDDEN + j];
        const float i_n = red_i[2] + b_ih[2 * HIDDEN + j];
        const float h_r = red_h[0] + b_hh[j];
        const float h_z = red_h[1] + b_hh[HIDDEN + j];
        const float h_n = red_h[2] + b_hh[2 * HIDDEN + j];
        const float r = 1.f / (1.f + expf(-(i_r + h_r)));
        const float z = 1.f / (1.f + expf(-(i_z + h_z)));
        const float n = tanhf(i_n + r * h_n);
        const float hv = (1.f - z) * n + z * hidden[j];
        h_new_out[j] = hv;
        h_new_ws[j] = hv;
    }
}

// K2: logits[v] = h_new . w_out[v] + b_out[v]. Each wave owns a CONTIGUOUS
// chunk of 6-7 rows (balanced), 2-row ILP inside the chunk -> sequential 8KB
// bursts per wave. Fused per-block online (max,sumexp) partials. No fences.
__global__ __launch_bounds__(256) void logits_kernel(
    const float* __restrict__ h_new, const float* __restrict__ w_out,
    const float* __restrict__ b_out, float* __restrict__ logits,
    float* __restrict__ partials) {
    const int wave = threadIdx.x >> 6;
    const int lane = threadIdx.x & 63;
    const int gw = blockIdx.x * 4 + wave;   // 0..NW-1

    // balanced contiguous chunks: first EXTRA waves take BASE+1 rows
    const int BASE = VOCAB / NW;             // 6
    const int EXTRA = VOCAB - BASE * NW;     // 1105
    const int start = gw * BASE + (gw < EXTRA ? gw : EXTRA);
    const int end = start + BASE + (gw < EXTRA ? 1 : 0);

    const float4* h4 = (const float4*)h_new;  // 16B-aligned ws staging copy
    float4 hs[4];
#pragma unroll
    for (int k = 0; k < 4; ++k) hs[k] = h4[k * 64 + lane];

    float m = -INFINITY, s = 0.f;
    int v = start;
    for (; v + 1 < end; v += 2) {
        const float4* w1 = (const float4*)(w_out + (size_t)v * HIDDEN);
        const float4* w2 = (const float4*)(w_out + (size_t)(v + 1) * HIDDEN);
        float a1 = 0.f, a2 = 0.f;
#pragma unroll
        for (int k = 0; k < 4; ++k) {
            const int idx = k * 64 + lane;
            float4 x = w1[idx];
            float4 y = w2[idx];
            a1 += x.x * hs[k].x + x.y * hs[k].y + x.z * hs[k].z + x.w * hs[k].w;
            a2 += y.x * hs[k].x + y.y * hs[k].y + y.z * hs[k].z + y.w * hs[k].w;
        }
        a1 = wave_reduce_sum(a1);
        a2 = wave_reduce_sum(a2);

        const float l1 = a1 + b_out[v];
        const float l2 = a2 + b_out[v + 1];
        if (lane == 0) { logits[v] = l1; logits[v + 1] = l2; }
        const float mx = fmaxf(l1, l2);
        if (mx > m) { s *= expf(m - mx); m = mx; }
        s += expf(l1 - m) + expf(l2 - m);
    }
    if (v < end) {  // odd tail row
        const float4* w1 = (const float4*)(w_out + (size_t)v * HIDDEN);
        float a1 = 0.f;
#pragma unroll
        for (int k = 0; k < 4; ++k) {
            const int idx = k * 64 + lane;
            float4 x = w1[idx];
            a1 += x.x * hs[k].x + x.y * hs[k].y + x.z * hs[k].z + x.w * hs[k].w;
        }
        a1 = wave_reduce_sum(a1);
        const float l1 = a1 + b_out[v];
        if (lane == 0) logits[v] = l1;
        if (l1 > m) { s *= expf(m - l1); m = l1; }
        s += expf(l1 - m);
    }

    __shared__ float sm[4], ss[4];
    if (lane == 0) { sm[wave] = m; ss[wave] = s; }
    __syncthreads();
    if (threadIdx.x == 0) {
        float M = fmaxf(fmaxf(sm[0], sm[1]), fmaxf(sm[2], sm[3]));
        float S = ss[0] * expf(sm[0] - M) + ss[1] * expf(sm[1] - M) +
                  ss[2] * expf(sm[2] - M) + ss[3] * expf(sm[3] - M);
        partials[2 * blockIdx.x] = M;
        partials[2 * blockIdx.x + 1] = S;
    }
}

// K3: every block redundantly combines the K2_BLOCKS (m,s) pairs (16KB, L2-hot),
// then subtracts the LSE from its slice of logits.
__global__ __launch_bounds__(256) void finalize_kernel(
    const float* __restrict__ partials, float* __restrict__ logits) {
    const int t = threadIdx.x;
    const int wave = t >> 6;
    const int lane = t & 63;

    float m = -INFINITY, s = 0.f;
#pragma unroll
    for (int i = 0; i < K2_BLOCKS / 256; ++i) {
        const int idx = i * 256 + t;
        const float pm = partials[2 * idx];
        const float ps = partials[2 * idx + 1];
        const float M = fmaxf(m, pm);
        s = s * expf(m - M) + ps * expf(pm - M);
        m = M;
    }
#pragma unroll
    for (int o = 1; o < 64; o <<= 1) {
        const float pm = __shfl_xor(m, o, 64);
        const float ps = __shfl_xor(s, o, 64);
        const float M = fmaxf(m, pm);
        s = s * expf(m - M) + ps * expf(pm - M);
        m = M;
    }
    __shared__ float sm[4], ss[4];
    if (lane == 0) { sm[wave] = m; ss[wave] = s; }
    __syncthreads();
    const float M = fmaxf(fmaxf(sm[0], sm[1]), fmaxf(sm[2], sm[3]));
    const float S = ss[0] * expf(sm[0] - M) + ss[1] * expf(sm[1] - M) +
                    ss[2] * expf(sm[2] - M) + ss[3] * expf(sm[3] - M);
    const float c = M + logf(S);

    // subtract: float4 over [0, 50256), scalar tail for element 50256
    float4* l4 = (float4*)logits;
    const int n4 = VOCAB / 4;  // 12564
    for (int i = blockIdx.x * 256 + t; i < n4; i += gridDim.x * 256) {
        float4 x = l4[i];
        x.x -= c; x.y -= c; x.z -= c; x.w -= c;
        l4[i] = x;
    }
    if (blockIdx.x == 0 && t == 0) logits[VOCAB - 1] -= c;
}

extern "C" void kernel_launch(void* const* d_in, const int* in_sizes, int n_in,
                              void* d_out, int out_size, void* d_ws, size_t ws_size,
                              hipStream_t stream) {
    const int*   token  = (const int*)d_in[0];
    const float* hidden = (const float*)d_in[1];
    const float* emb    = (const float*)d_in[2];
    const float* w_ih   = (const float*)d_in[3];
    const float* w_hh   = (const float*)d_in[4];
    const float* b_ih   = (const float*)d_in[5];
    const float* b_hh   = (const float*)d_in[6];
    const float* w_out  = (const float*)d_in[7];
    const float* b_out  = (const float*)d_in[8];

    float* out      = (float*)d_out;        // [0..V)=logp, [V..V+H)=h_new
    float* h_new    = out + VOCAB;
    float* logits   = out;
    float* ws       = (float*)d_ws;
    float* partials = ws;                   // 2*K2_BLOCKS floats
    float* h_new_ws = ws + 2 * K2_BLOCKS;   // HIDDEN floats, 16B-aligned

    gru_kernel<<<HIDDEN, 192, 0, stream>>>(token, hidden, emb, w_ih, w_hh,
                                           b_ih, b_hh, h_new, h_new_ws);
    logits_kernel<<<K2_BLOCKS, 256, 0, stream>>>(h_new_ws, w_out, b_out, logits,
                                                 partials);
    finalize_kernel<<<64, 256, 0, stream>>>(partials, logits);
}